// Round 14
// baseline (417.408 us; speedup 1.0000x reference)
//
#include <hip/hip_runtime.h>
#include <hip/hip_bf16.h>

#define EDGES 100000
#define TRIPS 500000
#define HC 128
#define IC 64
#define NRC 6
#define SBF_K 42
#define T_K 294
#define T_KSTEPS 10
#define S_KSTEPS 2

typedef __attribute__((ext_vector_type(8))) short bf16x8;
typedef __attribute__((ext_vector_type(4))) float f32x4;
typedef __attribute__((ext_vector_type(2))) float f32x2;

__device__ __forceinline__ float selu_f(float x) {
    const float scale = 1.0507009873554805f;
    const float alpha = 1.6732632423543772f;
    return x > 0.f ? scale * x : scale * alpha * expm1f(x);
}

__device__ __forceinline__ unsigned short f2bf(float f) {
    unsigned int u = __float_as_uint(f);
    u += 0x7fffu + ((u >> 16) & 1u);
    return (unsigned short)(u >> 16);
}

__device__ __forceinline__ unsigned cvtpk(float a, float b) {
    unsigned o;
    asm("v_cvt_pk_bf16_f32 %0, %1, %2" : "=v"(o) : "v"(a), "v"(b));
    return o;
}

// async global->LDS, 16B per lane
__device__ __forceinline__ void gl_lds16(const char* g, char* l) {
    __builtin_amdgcn_global_load_lds(
        (const __attribute__((address_space(1))) void*)g,
        (__attribute__((address_space(3))) void*)l, 16, 0, 0);
}

// swizzled bf16 activation tile [rows][128 cols], row stride 256B
__device__ __forceinline__ bf16x8 ldsA(const unsigned short* act, int row, int kbf) {
    int byte = row * 256 + kbf * 2;
    byte ^= (row & 7) << 4;
    return *(const bf16x8*)((const char*)act + byte);
}
__device__ __forceinline__ void ldsW(unsigned short* act, int row, int col, unsigned short v) {
    int byte = row * 256 + col * 2;
    byte ^= (row & 7) << 4;
    *(unsigned short*)((char*)act + byte) = v;
}
__device__ __forceinline__ void ldsW8B(unsigned short* act, int row, int col4,
                                       float a, float b, float c, float d) {
    unsigned long long v = (unsigned long long)(f2bf(a) | ((unsigned)f2bf(b) << 16)) |
                           ((unsigned long long)(f2bf(c) | ((unsigned)f2bf(d) << 16)) << 32);
    int byte = row * 256 + col4 * 8;
    byte ^= (row & 7) << 4;
    *(unsigned long long*)((char*)act + byte) = v;
}

template <int KS>
__device__ __forceinline__ void mm2(const unsigned short* act, const bf16x8* B,
                                    int lane, f32x4* acc) {
    const int ar = lane & 15;
    const int koff = (lane >> 4) * 8;
#pragma unroll
    for (int mt = 0; mt < 2; mt++) {
        f32x4 c = {0.f, 0.f, 0.f, 0.f};
#pragma unroll
        for (int ks = 0; ks < KS; ks++) {
            bf16x8 a = ldsA(act, mt * 16 + ar, ks * 32 + koff);
            c = __builtin_amdgcn_mfma_f32_16x16x32_bf16(a, B[ks], c, 0, 0, 0);
        }
        acc[mt] = c;
    }
}

// ---------------- combos: combined weights + fragment packs ----------------
__device__ __forceinline__ void pack_w(const float* __restrict__ W, int K, int N,
                                       unsigned short* __restrict__ dst, int tid, int stride) {
    const int nt = N >> 4;
    const int total = (K >> 5) * nt * 512;
    for (int idx = tid; idx < total; idx += stride) {
        int j = idx & 7, l = (idx >> 3) & 63;
        int t = idx >> 9;
        int n = t % nt, ks = t / nt;
        int k = ks * 32 + ((l >> 4) << 3) + j;
        int c = n * 16 + (l & 15);
        dst[idx] = f2bf(W[k * N + c]);
    }
}

__global__ void combos_kernel(const float* __restrict__ W_rbf1, const float* __restrict__ W_rbf2,
                              const float* __restrict__ W_sbf1, const float* __restrict__ W_sbf2,
                              const float* __restrict__ W_t1,   const float* __restrict__ W_t2,
                              const float* __restrict__ W_ji,   const float* __restrict__ W_kj,
                              const float* __restrict__ W_down, const float* __restrict__ W_up,
                              const float* __restrict__ resbW1, const float* __restrict__ resbW2,
                              const float* __restrict__ W_lin,
                              const float* __restrict__ resaW1, const float* __restrict__ resaW2,
                              float* __restrict__ Wrbf_c,
                              unsigned short* __restrict__ Wt_pack,
                              unsigned short* __restrict__ Ws_pack,
                              unsigned short* __restrict__ Pji, unsigned short* __restrict__ Pkj,
                              unsigned short* __restrict__ Pdown, unsigned short* __restrict__ Pup,
                              unsigned short* __restrict__ Prb1, unsigned short* __restrict__ Prb2,
                              unsigned short* __restrict__ Plin,
                              unsigned short* __restrict__ Pra10, unsigned short* __restrict__ Pra20,
                              unsigned short* __restrict__ Pra11, unsigned short* __restrict__ Pra21) {
    int tid = blockIdx.x * blockDim.x + threadIdx.x;
    int stride = gridDim.x * blockDim.x;
    for (int idx = tid; idx < NRC * HC; idx += stride) {
        int r = idx / HC, h = idx % HC;
        float s = 0.f;
        for (int b = 0; b < 8; b++) s += W_rbf1[r * 8 + b] * W_rbf2[b * HC + h];
        Wrbf_c[idx] = s;
    }
    for (int idx = tid; idx < T_KSTEPS * 4 * 64 * 8; idx += stride) {
        int j = idx & 7, l = (idx >> 3) & 63, n = (idx >> 9) & 3, s = idx >> 11;
        int k = s * 32 + (l >> 4) * 8 + j;
        int c = n * 16 + (l & 15);
        float v = 0.f;
        if (k < T_K)
            for (int b = 0; b < 8; b++) v += W_t1[k * 8 + b] * W_t2[b * IC + c];
        Wt_pack[idx] = f2bf(v);
    }
    for (int idx = tid; idx < S_KSTEPS * 4 * 64 * 8; idx += stride) {
        int j = idx & 7, l = (idx >> 3) & 63, n = (idx >> 9) & 3, s = idx >> 11;
        int k = s * 32 + (l >> 4) * 8 + j;
        int c = n * 16 + (l & 15);
        float v = 0.f;
        if (k < SBF_K)
            for (int b = 0; b < 8; b++) v += W_sbf1[k * 8 + b] * W_sbf2[b * IC + c];
        Ws_pack[idx] = f2bf(v);
    }
    pack_w(W_ji,   HC, HC, Pji,   tid, stride);
    pack_w(W_kj,   HC, HC, Pkj,   tid, stride);
    pack_w(W_down, HC, IC, Pdown, tid, stride);
    pack_w(W_up,   IC, HC, Pup,   tid, stride);
    pack_w(resbW1, HC, HC, Prb1,  tid, stride);
    pack_w(resbW2, HC, HC, Prb2,  tid, stride);
    pack_w(W_lin,  HC, HC, Plin,  tid, stride);
    pack_w(resaW1,           HC, HC, Pra10, tid, stride);
    pack_w(resaW2,           HC, HC, Pra20, tid, stride);
    pack_w(resaW1 + HC * HC, HC, HC, Pra11, tid, stride);
    pack_w(resaW2 + HC * HC, HC, HC, Pra21, tid, stride);
}

// ---------------- edge front (MFMA) + seg zeroing ----------------
__global__ __launch_bounds__(512) void edge_front_mfma(
    const float* __restrict__ x1, const float* __restrict__ rbf0,
    const unsigned short* __restrict__ Pji, const unsigned short* __restrict__ Pkj,
    const unsigned short* __restrict__ Pdown,
    const float* __restrict__ bji, const float* __restrict__ bkj,
    const float* __restrict__ Wrbf_c,
    float* __restrict__ xji_out, float* __restrict__ xkjd_out,
    float* __restrict__ seg) {
    __shared__ __align__(16) unsigned short act[32 * 128];
    __shared__ float rbfs[32][8];
    const int tid = threadIdx.x;
    const int lane = tid & 63;
    const int w = tid >> 6;
    const int e0 = blockIdx.x * 32;

    ((float4*)(seg + (size_t)e0 * IC))[tid] = float4{0.f, 0.f, 0.f, 0.f};

    bf16x8 Bji[4], Bkj[4];
#pragma unroll
    for (int ks = 0; ks < 4; ks++) {
        Bji[ks] = *(const bf16x8*)(Pji + (size_t)((ks * 8 + w) * 64 + lane) * 8);
        Bkj[ks] = *(const bf16x8*)(Pkj + (size_t)((ks * 8 + w) * 64 + lane) * 8);
    }
    const int ntd = w & 3, mtd = w >> 2;
    bf16x8 Bd[4];
#pragma unroll
    for (int ks = 0; ks < 4; ks++)
        Bd[ks] = *(const bf16x8*)(Pdown + (size_t)((ks * 4 + ntd) * 64 + lane) * 8);

    {
        const float4* s4 = (const float4*)(x1 + (size_t)e0 * HC);
#pragma unroll
        for (int i = tid; i < 1024; i += 512) {
            float4 v = s4[i];
            ldsW8B(act, i >> 5, i & 31, v.x, v.y, v.z, v.w);
        }
        if (tid < 192) rbfs[tid / 6][tid % 6] = rbf0[(size_t)e0 * NRC + tid];
    }
    __syncthreads();

    const int ar = lane & 15;
    const int koff = (lane >> 4) * 8;
    f32x4 aj[2], ak[2];
#pragma unroll
    for (int mt = 0; mt < 2; mt++) {
        f32x4 cj = {0.f, 0.f, 0.f, 0.f};
        f32x4 ck = {0.f, 0.f, 0.f, 0.f};
#pragma unroll
        for (int ks = 0; ks < 4; ks++) {
            bf16x8 a = ldsA(act, mt * 16 + ar, ks * 32 + koff);
            cj = __builtin_amdgcn_mfma_f32_16x16x32_bf16(a, Bji[ks], cj, 0, 0, 0);
            ck = __builtin_amdgcn_mfma_f32_16x16x32_bf16(a, Bkj[ks], ck, 0, 0, 0);
        }
        aj[mt] = cj; ak[mt] = ck;
    }
    __syncthreads();

    const int ch = w * 16 + (lane & 15);
    const int rg = (lane >> 4) * 4;
    {
        float bjv = bji[ch], bkv = bkj[ch];
        float wr[6];
#pragma unroll
        for (int q = 0; q < 6; q++) wr[q] = Wrbf_c[q * HC + ch];
#pragma unroll
        for (int mt = 0; mt < 2; mt++) {
#pragma unroll
            for (int r = 0; r < 4; r++) {
                int m = mt * 16 + rg + r;
                float rv = 0.f;
#pragma unroll
                for (int q = 0; q < 6; q++) rv += rbfs[m][q] * wr[q];
                xji_out[(size_t)(e0 + m) * HC + ch] = selu_f(aj[mt][r] + bjv);
                float xk = selu_f(ak[mt][r] + bkv) * rv;
                ldsW(act, m, ch, f2bf(xk));
            }
        }
    }
    __syncthreads();

    f32x4 cd = {0.f, 0.f, 0.f, 0.f};
#pragma unroll
    for (int ks = 0; ks < 4; ks++) {
        bf16x8 a = ldsA(act, mtd * 16 + ar, ks * 32 + koff);
        cd = __builtin_amdgcn_mfma_f32_16x16x32_bf16(a, Bd[ks], cd, 0, 0, 0);
    }
    const int chd = ntd * 16 + (lane & 15);
#pragma unroll
    for (int r = 0; r < 4; r++)
        xkjd_out[(size_t)(e0 + mtd * 16 + rg + r) * IC + chd] = selu_f(cd[r]);
}

// ---------------- triplet v9: 8-trip slabs, ping-pong global_load_lds, 1 barrier/slab ----------------
// buffer: t [8 x 1176B] + s [8 x 168B] = 10752B; two buffers + idx = ~21.6KB -> 7 blocks/CU
#define T3_IMG_B 9408
#define S3_IMG_B 1344
#define BUF_B (T3_IMG_B + S3_IMG_B)
__global__ __launch_bounds__(256) void triplet_mfma9(
    const float* __restrict__ sbf, const float* __restrict__ tmat,
    const unsigned short* __restrict__ Wt_pack,
    const unsigned short* __restrict__ Ws_pack,
    const float* __restrict__ xkjd,
    const int* __restrict__ idx_kj, const int* __restrict__ idx_ji,
    float* __restrict__ seg, int nslab) {
    __shared__ __align__(16) char lds[2 * BUF_B + 128];
    int* kj0 = (int*)(lds + 2 * BUF_B);        // kj[2][8], ji[2][8]
    const int tid = threadIdx.x;
    const int lane = tid & 63;
    const int w = tid >> 6;       // wave = ch-tile
    const int lr = lane & 15;
    const int lq = lane >> 4;
    const int ch = w * 16 + lr;

    // weight fragments as B operand: 48 VGPR, resident
    bf16x8 bt_w[T_KSTEPS], bs_w[S_KSTEPS];
#pragma unroll
    for (int s = 0; s < T_KSTEPS; s++)
        bt_w[s] = *(const bf16x8*)(Wt_pack + (size_t)((s * 4 + w) * 64 + lane) * 8);
#pragma unroll
    for (int s = 0; s < S_KSTEPS; s++)
        bs_w[s] = *(const bf16x8*)(Ws_pack + (size_t)((s * 4 + w) * 64 + lane) * 8);

#define STAGE(B, SLAB)                                                             \
    {                                                                              \
        const char* tsrc = (const char*)tmat + (size_t)(SLAB) * T3_IMG_B;          \
        const char* ssrc = (const char*)sbf + (size_t)(SLAB) * S3_IMG_B;           \
        char* tb = lds + (B) * BUF_B;                                              \
        char* sb = tb + T3_IMG_B;                                                  \
        for (int i = w; i < 12; i += 4) {                                          \
            if (i < 10) {                                                          \
                int off = i * 1024 + lane * 16;                                    \
                if (off < T3_IMG_B) gl_lds16(tsrc + off, tb + off);                \
            } else {                                                               \
                int off = (i - 10) * 1024 + lane * 16;                             \
                if (off < S3_IMG_B) gl_lds16(ssrc + off, sb + off);                \
            }                                                                      \
        }                                                                          \
        if (tid < 8) {                                                             \
            kj0[(B) * 8 + tid]      = idx_kj[(size_t)(SLAB) * 8 + tid];            \
            kj0[16 + (B) * 8 + tid] = idx_ji[(size_t)(SLAB) * 8 + tid];            \
        }                                                                          \
    }

    int slab = blockIdx.x;
    if (slab < nslab) STAGE(0, slab)
    __syncthreads();

    int it = 0;
    for (; slab < nslab; slab += gridDim.x, it ^= 1) {
        int nxt = slab + gridDim.x;
        if (nxt < nslab) STAGE(it ^ 1, nxt)

        // ---- compute slab from buffer `it` (A rows clamped to 0..7) ----
        f32x4 acc_t = {0.f, 0.f, 0.f, 0.f};
        f32x4 acc_s = {0.f, 0.f, 0.f, 0.f};
        {
            const char* tp = lds + it * BUF_B + (lr & 7) * 1176 + lq * 32;
#pragma unroll
            for (int ks = 0; ks < T_KSTEPS; ks++) {
                f32x2 p0 = *(const f32x2*)(tp + ks * 128);
                f32x2 p1 = *(const f32x2*)(tp + ks * 128 + 8);
                f32x2 p2 = *(const f32x2*)(tp + ks * 128 + 16);
                f32x2 p3 = *(const f32x2*)(tp + ks * 128 + 24);
                union { unsigned u[4]; bf16x8 v; } a;
                a.u[0] = cvtpk(p0.x, p0.y); a.u[1] = cvtpk(p1.x, p1.y);
                a.u[2] = cvtpk(p2.x, p2.y); a.u[3] = cvtpk(p3.x, p3.y);
                acc_t = __builtin_amdgcn_mfma_f32_16x16x32_bf16(a.v, bt_w[ks], acc_t, 0, 0, 0);
            }
            const char* sp = lds + it * BUF_B + T3_IMG_B + (lr & 7) * 168 + lq * 32;
#pragma unroll
            for (int ks = 0; ks < S_KSTEPS; ks++) {
                f32x2 p0 = *(const f32x2*)(sp + ks * 128);
                f32x2 p1 = *(const f32x2*)(sp + ks * 128 + 8);
                f32x2 p2 = *(const f32x2*)(sp + ks * 128 + 16);
                f32x2 p3 = *(const f32x2*)(sp + ks * 128 + 24);
                union { unsigned u[4]; bf16x8 v; } a;
                a.u[0] = cvtpk(p0.x, p0.y); a.u[1] = cvtpk(p1.x, p1.y);
                a.u[2] = cvtpk(p2.x, p2.y); a.u[3] = cvtpk(p3.x, p3.y);
                acc_s = __builtin_amdgcn_mfma_f32_16x16x32_bf16(a.v, bs_w[ks], acc_s, 0, 0, 0);
            }
        }

        // ---- epilogue: trips 0..7 only (lq 0,1), dense 16-ch atomics ----
        if (lq < 2) {
#pragma unroll
            for (int r = 0; r < 4; r++) {
                int ml = lq * 4 + r;
                float y = xkjd[(size_t)kj0[it * 8 + ml] * IC + ch] * acc_s[r] * acc_t[r];
                atomicAdd(&seg[(size_t)kj0[16 + it * 8 + ml] * IC + ch], y);
            }
        }
        __syncthreads();   // drains next-slab staging; guards buffer reuse
    }
#undef STAGE
}

// ---------------- edge back: M=32, stage-wise weight double-buffer, 2 blocks/CU ----------------
__global__ __launch_bounds__(512, 4) void edge_back_mfma(
    const float* __restrict__ seg, const float* __restrict__ xji,
    const float* __restrict__ x1, const float* __restrict__ rbf0,
    const unsigned short* __restrict__ Pup,
    const unsigned short* __restrict__ Prb1, const unsigned short* __restrict__ Prb2,
    const unsigned short* __restrict__ Plin,
    const unsigned short* __restrict__ Pra10, const unsigned short* __restrict__ Pra20,
    const unsigned short* __restrict__ Pra11, const unsigned short* __restrict__ Pra21,
    const float* __restrict__ bb1, const float* __restrict__ bb2,
    const float* __restrict__ blin,
    const float* __restrict__ ba1, const float* __restrict__ ba2,
    const float* __restrict__ Wrbf,
    float* __restrict__ e1_out, float* __restrict__ e2_out) {
    __shared__ __align__(16) unsigned short act[32 * 128];
    __shared__ float rbfs[32][8];
    const int tid = threadIdx.x;
    const int lane = tid & 63;
    const int w = tid >> 6;
    const int e0 = blockIdx.x * 32;
    const int ch = w * 16 + (lane & 15);
    const int rg = (lane >> 4) * 4;

    bf16x8 BA[4], BB[4];
#define LOADW(DST, P, N)                                                        \
    _Pragma("unroll")                                                           \
    for (int ks = 0; ks < N; ks++)                                              \
        DST[ks] = *(const bf16x8*)((P) + (size_t)((ks * 8 + w) * 64 + lane) * 8);

    LOADW(BA, Pup, 2)

    {
        const float4* s4 = (const float4*)(seg + (size_t)e0 * IC);
        float4 v = s4[tid];
        ldsW8B(act, tid >> 4, tid & 15, v.x, v.y, v.z, v.w);
        if (tid < 192) rbfs[tid / 6][tid % 6] = rbf0[(size_t)e0 * NRC + tid];
    }
    float skip[2][4], x1v[2][4];
#pragma unroll
    for (int mt = 0; mt < 2; mt++)
#pragma unroll
        for (int r = 0; r < 4; r++) {
            skip[mt][r] = xji[(size_t)(e0 + mt * 16 + rg + r) * HC + ch];
            x1v[mt][r]  = x1 [(size_t)(e0 + mt * 16 + rg + r) * HC + ch];
        }
    __syncthreads();

    f32x4 acc[2];
    float h[2][4];

    mm2<2>(act, BA, lane, acc);
    LOADW(BB, Prb1, 4)
    __syncthreads();
#pragma unroll
    for (int mt = 0; mt < 2; mt++)
#pragma unroll
        for (int r = 0; r < 4; r++) {
            h[mt][r] = selu_f(acc[mt][r]) + skip[mt][r];
            ldsW(act, mt * 16 + rg + r, ch, f2bf(h[mt][r]));
            skip[mt][r] = h[mt][r];
        }
    __syncthreads();

    mm2<4>(act, BB, lane, acc);
    LOADW(BA, Prb2, 4)
    __syncthreads();
    {
        float bv = bb1[ch];
#pragma unroll
        for (int mt = 0; mt < 2; mt++)
#pragma unroll
            for (int r = 0; r < 4; r++)
                ldsW(act, mt * 16 + rg + r, ch, f2bf(selu_f(acc[mt][r] + bv)));
    }
    __syncthreads();

    mm2<4>(act, BA, lane, acc);
    LOADW(BB, Plin, 4)
    __syncthreads();
    {
        float bv = bb2[ch];
#pragma unroll
        for (int mt = 0; mt < 2; mt++)
#pragma unroll
            for (int r = 0; r < 4; r++) {
                h[mt][r] = skip[mt][r] + selu_f(acc[mt][r] + bv);
                ldsW(act, mt * 16 + rg + r, ch, f2bf(h[mt][r]));
            }
    }
    __syncthreads();

    mm2<4>(act, BB, lane, acc);
    LOADW(BA, Pra10, 4)
    __syncthreads();
    {
        float bv = blin[ch];
#pragma unroll
        for (int mt = 0; mt < 2; mt++)
#pragma unroll
            for (int r = 0; r < 4; r++) {
                h[mt][r] = selu_f(acc[mt][r] + bv) + x1v[mt][r];
                ldsW(act, mt * 16 + rg + r, ch, f2bf(h[mt][r]));
                skip[mt][r] = h[mt][r];
            }
    }
    __syncthreads();

    mm2<4>(act, BA, lane, acc);
    LOADW(BB, Pra20, 4)
    __syncthreads();
    {
        float bv = ba1[ch];
#pragma unroll
        for (int mt = 0; mt < 2; mt++)
#pragma unroll
            for (int r = 0; r < 4; r++)
                ldsW(act, mt * 16 + rg + r, ch, f2bf(selu_f(acc[mt][r] + bv)));
    }
    __syncthreads();

    mm2<4>(act, BB, lane, acc);
    LOADW(BA, Pra11, 4)
    __syncthreads();
    {
        float bv = ba2[ch];
#pragma unroll
        for (int mt = 0; mt < 2; mt++)
#pragma unroll
            for (int r = 0; r < 4; r++) {
                h[mt][r] = skip[mt][r] + selu_f(acc[mt][r] + bv);
                ldsW(act, mt * 16 + rg + r, ch, f2bf(h[mt][r]));
                skip[mt][r] = h[mt][r];
            }
    }
    __syncthreads();

    mm2<4>(act, BA, lane, acc);
    LOADW(BB, Pra21, 4)
    __syncthreads();
    {
        float bv = ba1[HC + ch];
#pragma unroll
        for (int mt = 0; mt < 2; mt++)
#pragma unroll
            for (int r = 0; r < 4; r++)
                ldsW(act, mt * 16 + rg + r, ch, f2bf(selu_f(acc[mt][r] + bv)));
    }
    __syncthreads();

    mm2<4>(act, BB, lane, acc);
    {
        float bv = ba2[HC + ch];
        float wr[6];
#pragma unroll
        for (int q = 0; q < 6; q++) wr[q] = Wrbf[q * HC + ch];
#pragma unroll
        for (int mt = 0; mt < 2; mt++)
#pragma unroll
            for (int r = 0; r < 4; r++) {
                int m = mt * 16 + rg + r;
                float v = skip[mt][r] + selu_f(acc[mt][r] + bv);
                float rv = 0.f;
#pragma unroll
                for (int q = 0; q < 6; q++) rv += rbfs[m][q] * wr[q];
                size_t e = (size_t)(e0 + m);
                e1_out[e * HC + ch] = v;
                e2_out[e * HC + ch] = rv * v;
            }
    }
#undef LOADW
}

extern "C" void kernel_launch(void* const* d_in, const int* in_sizes, int n_in,
                              void* d_out, int out_size, void* d_ws, size_t ws_size,
                              hipStream_t stream) {
    const float* x1     = (const float*)d_in[0];
    const float* rbf0   = (const float*)d_in[1];
    const float* sbf    = (const float*)d_in[2];
    const float* tmat   = (const float*)d_in[3];
    const float* W_rbf1 = (const float*)d_in[5];
    const float* W_rbf2 = (const float*)d_in[6];
    const float* W_sbf1 = (const float*)d_in[7];
    const float* W_sbf2 = (const float*)d_in[8];
    const float* W_t1   = (const float*)d_in[9];
    const float* W_t2   = (const float*)d_in[10];
    const float* W_rbf  = (const float*)d_in[11];
    const float* W_kj   = (const float*)d_in[12];
    const float* b_kj   = (const float*)d_in[13];
    const float* W_ji   = (const float*)d_in[14];
    const float* b_ji   = (const float*)d_in[15];
    const float* W_down = (const float*)d_in[16];
    const float* W_up   = (const float*)d_in[17];
    const float* W_lin  = (const float*)d_in[18];
    const float* b_lin  = (const float*)d_in[19];
    const float* resbW1 = (const float*)d_in[20];
    const float* resbb1 = (const float*)d_in[21];
    const float* resbW2 = (const float*)d_in[22];
    const float* resbb2 = (const float*)d_in[23];
    const float* resaW1 = (const float*)d_in[24];
    const float* resab1 = (const float*)d_in[25];
    const float* resaW2 = (const float*)d_in[26];
    const float* resab2 = (const float*)d_in[27];
    const int* idx_kj   = (const int*)d_in[28];
    const int* idx_ji   = (const int*)d_in[29];

    float* ws = (float*)d_ws;
    float* Wrbf_c = ws;                                    // 768 f32
    unsigned short* u0 = (unsigned short*)(ws + 768);
    unsigned short* Wt_pack = u0;              // 20480
    unsigned short* Ws_pack = Wt_pack + 20480; // 4096
    unsigned short* Pji   = Ws_pack + 4096;    // 16384
    unsigned short* Pkj   = Pji + 16384;
    unsigned short* Pdown = Pkj + 16384;       // 8192
    unsigned short* Pup   = Pdown + 8192;      // 8192
    unsigned short* Prb1  = Pup + 8192;        // 16384
    unsigned short* Prb2  = Prb1 + 16384;
    unsigned short* Plin  = Prb2 + 16384;
    unsigned short* Pra10 = Plin + 16384;
    unsigned short* Pra20 = Pra10 + 16384;
    unsigned short* Pra11 = Pra20 + 16384;
    unsigned short* Pra21 = Pra11 + 16384;
    float* xkjd = ws + 768 + 94208;
    float* seg  = xkjd + (size_t)EDGES * IC;

    float* e1_out = (float*)d_out;
    float* e2_out = e1_out + (size_t)EDGES * HC;
    float* xji    = e1_out;  // park x_ji in the e1 output region

    combos_kernel<<<64, 256, 0, stream>>>(W_rbf1, W_rbf2, W_sbf1, W_sbf2, W_t1, W_t2,
                                          W_ji, W_kj, W_down, W_up, resbW1, resbW2,
                                          W_lin, resaW1, resaW2,
                                          Wrbf_c, Wt_pack, Ws_pack,
                                          Pji, Pkj, Pdown, Pup, Prb1, Prb2, Plin,
                                          Pra10, Pra20, Pra11, Pra21);
    edge_front_mfma<<<EDGES / 32, 512, 0, stream>>>(x1, rbf0, Pji, Pkj, Pdown,
                                                    b_ji, b_kj, Wrbf_c, xji, xkjd, seg);
    triplet_mfma9<<<4096, 256, 0, stream>>>(sbf, tmat, Wt_pack, Ws_pack, xkjd,
                                            idx_kj, idx_ji, seg, TRIPS / 8);
    edge_back_mfma<<<EDGES / 32, 512, 0, stream>>>(seg, xji, x1, rbf0,
                                                   Pup, Prb1, Prb2, Plin,
                                                   Pra10, Pra20, Pra11, Pra21,
                                                   resbb1, resbb2, b_lin,
                                                   resab1, resab2, W_rbf,
                                                   e1_out, e2_out);
}

// Round 15
// 329.481 us; speedup vs baseline: 1.2669x; 1.2669x over previous
//
#include <hip/hip_runtime.h>
#include <hip/hip_bf16.h>

#define EDGES 100000
#define TRIPS 500000
#define HC 128
#define IC 64
#define NRC 6
#define SBF_K 42
#define T_K 294
#define T_KSTEPS 10
#define S_KSTEPS 2

typedef __attribute__((ext_vector_type(8))) short bf16x8;
typedef __attribute__((ext_vector_type(4))) float f32x4;
typedef __attribute__((ext_vector_type(2))) float f32x2;

__device__ __forceinline__ float selu_f(float x) {
    const float scale = 1.0507009873554805f;
    const float alpha = 1.6732632423543772f;
    return x > 0.f ? scale * x : scale * alpha * expm1f(x);
}

__device__ __forceinline__ unsigned short f2bf(float f) {
    unsigned int u = __float_as_uint(f);
    u += 0x7fffu + ((u >> 16) & 1u);
    return (unsigned short)(u >> 16);
}

__device__ __forceinline__ unsigned cvtpk(float a, float b) {
    unsigned o;
    asm("v_cvt_pk_bf16_f32 %0, %1, %2" : "=v"(o) : "v"(a), "v"(b));
    return o;
}

// async global->LDS, 16B per lane
__device__ __forceinline__ void gl_lds16(const char* g, char* l) {
    __builtin_amdgcn_global_load_lds(
        (const __attribute__((address_space(1))) void*)g,
        (__attribute__((address_space(3))) void*)l, 16, 0, 0);
}

// swizzled bf16 activation tile [rows][128 cols], row stride 256B
__device__ __forceinline__ bf16x8 ldsA(const unsigned short* act, int row, int kbf) {
    int byte = row * 256 + kbf * 2;
    byte ^= (row & 7) << 4;
    return *(const bf16x8*)((const char*)act + byte);
}
__device__ __forceinline__ void ldsW(unsigned short* act, int row, int col, unsigned short v) {
    int byte = row * 256 + col * 2;
    byte ^= (row & 7) << 4;
    *(unsigned short*)((char*)act + byte) = v;
}
__device__ __forceinline__ void ldsW8B(unsigned short* act, int row, int col4,
                                       float a, float b, float c, float d) {
    unsigned long long v = (unsigned long long)(f2bf(a) | ((unsigned)f2bf(b) << 16)) |
                           ((unsigned long long)(f2bf(c) | ((unsigned)f2bf(d) << 16)) << 32);
    int byte = row * 256 + col4 * 8;
    byte ^= (row & 7) << 4;
    *(unsigned long long*)((char*)act + byte) = v;
}

template <int KS>
__device__ __forceinline__ void mm2(const unsigned short* act, const bf16x8* B,
                                    int lane, f32x4* acc) {
    const int ar = lane & 15;
    const int koff = (lane >> 4) * 8;
#pragma unroll
    for (int mt = 0; mt < 2; mt++) {
        f32x4 c = {0.f, 0.f, 0.f, 0.f};
#pragma unroll
        for (int ks = 0; ks < KS; ks++) {
            bf16x8 a = ldsA(act, mt * 16 + ar, ks * 32 + koff);
            c = __builtin_amdgcn_mfma_f32_16x16x32_bf16(a, B[ks], c, 0, 0, 0);
        }
        acc[mt] = c;
    }
}

// ---------------- combos: combined weights + fragment packs ----------------
__device__ __forceinline__ void pack_w(const float* __restrict__ W, int K, int N,
                                       unsigned short* __restrict__ dst, int tid, int stride) {
    const int nt = N >> 4;
    const int total = (K >> 5) * nt * 512;
    for (int idx = tid; idx < total; idx += stride) {
        int j = idx & 7, l = (idx >> 3) & 63;
        int t = idx >> 9;
        int n = t % nt, ks = t / nt;
        int k = ks * 32 + ((l >> 4) << 3) + j;
        int c = n * 16 + (l & 15);
        dst[idx] = f2bf(W[k * N + c]);
    }
}

__global__ void combos_kernel(const float* __restrict__ W_rbf1, const float* __restrict__ W_rbf2,
                              const float* __restrict__ W_sbf1, const float* __restrict__ W_sbf2,
                              const float* __restrict__ W_t1,   const float* __restrict__ W_t2,
                              const float* __restrict__ W_ji,   const float* __restrict__ W_kj,
                              const float* __restrict__ W_down, const float* __restrict__ W_up,
                              const float* __restrict__ resbW1, const float* __restrict__ resbW2,
                              const float* __restrict__ W_lin,
                              const float* __restrict__ resaW1, const float* __restrict__ resaW2,
                              float* __restrict__ Wrbf_c,
                              unsigned short* __restrict__ Wt_pack,
                              unsigned short* __restrict__ Ws_pack,
                              unsigned short* __restrict__ Pji, unsigned short* __restrict__ Pkj,
                              unsigned short* __restrict__ Pdown, unsigned short* __restrict__ Pup,
                              unsigned short* __restrict__ Prb1, unsigned short* __restrict__ Prb2,
                              unsigned short* __restrict__ Plin,
                              unsigned short* __restrict__ Pra10, unsigned short* __restrict__ Pra20,
                              unsigned short* __restrict__ Pra11, unsigned short* __restrict__ Pra21) {
    int tid = blockIdx.x * blockDim.x + threadIdx.x;
    int stride = gridDim.x * blockDim.x;
    for (int idx = tid; idx < NRC * HC; idx += stride) {
        int r = idx / HC, h = idx % HC;
        float s = 0.f;
        for (int b = 0; b < 8; b++) s += W_rbf1[r * 8 + b] * W_rbf2[b * HC + h];
        Wrbf_c[idx] = s;
    }
    for (int idx = tid; idx < T_KSTEPS * 4 * 64 * 8; idx += stride) {
        int j = idx & 7, l = (idx >> 3) & 63, n = (idx >> 9) & 3, s = idx >> 11;
        int k = s * 32 + (l >> 4) * 8 + j;
        int c = n * 16 + (l & 15);
        float v = 0.f;
        if (k < T_K)
            for (int b = 0; b < 8; b++) v += W_t1[k * 8 + b] * W_t2[b * IC + c];
        Wt_pack[idx] = f2bf(v);
    }
    for (int idx = tid; idx < S_KSTEPS * 4 * 64 * 8; idx += stride) {
        int j = idx & 7, l = (idx >> 3) & 63, n = (idx >> 9) & 3, s = idx >> 11;
        int k = s * 32 + (l >> 4) * 8 + j;
        int c = n * 16 + (l & 15);
        float v = 0.f;
        if (k < SBF_K)
            for (int b = 0; b < 8; b++) v += W_sbf1[k * 8 + b] * W_sbf2[b * IC + c];
        Ws_pack[idx] = f2bf(v);
    }
    pack_w(W_ji,   HC, HC, Pji,   tid, stride);
    pack_w(W_kj,   HC, HC, Pkj,   tid, stride);
    pack_w(W_down, HC, IC, Pdown, tid, stride);
    pack_w(W_up,   IC, HC, Pup,   tid, stride);
    pack_w(resbW1, HC, HC, Prb1,  tid, stride);
    pack_w(resbW2, HC, HC, Prb2,  tid, stride);
    pack_w(W_lin,  HC, HC, Plin,  tid, stride);
    pack_w(resaW1,           HC, HC, Pra10, tid, stride);
    pack_w(resaW2,           HC, HC, Pra20, tid, stride);
    pack_w(resaW1 + HC * HC, HC, HC, Pra11, tid, stride);
    pack_w(resaW2 + HC * HC, HC, HC, Pra21, tid, stride);
}

// ---------------- edge front (MFMA, deferred Bd loads, 2 blocks/CU) ----------------
__global__ __launch_bounds__(512, 4) void edge_front_mfma(
    const float* __restrict__ x1, const float* __restrict__ rbf0,
    const unsigned short* __restrict__ Pji, const unsigned short* __restrict__ Pkj,
    const unsigned short* __restrict__ Pdown,
    const float* __restrict__ bji, const float* __restrict__ bkj,
    const float* __restrict__ Wrbf_c,
    float* __restrict__ xji_out, float* __restrict__ xkjd_out,
    float* __restrict__ seg) {
    __shared__ __align__(16) unsigned short act[32 * 128];
    __shared__ float rbfs[32][8];
    const int tid = threadIdx.x;
    const int lane = tid & 63;
    const int w = tid >> 6;
    const int e0 = blockIdx.x * 32;

    ((float4*)(seg + (size_t)e0 * IC))[tid] = float4{0.f, 0.f, 0.f, 0.f};

    bf16x8 Bji[4], Bkj[4];
#pragma unroll
    for (int ks = 0; ks < 4; ks++) {
        Bji[ks] = *(const bf16x8*)(Pji + (size_t)((ks * 8 + w) * 64 + lane) * 8);
        Bkj[ks] = *(const bf16x8*)(Pkj + (size_t)((ks * 8 + w) * 64 + lane) * 8);
    }
    const int ntd = w & 3, mtd = w >> 2;

    {
        const float4* s4 = (const float4*)(x1 + (size_t)e0 * HC);
#pragma unroll
        for (int i = tid; i < 1024; i += 512) {
            float4 v = s4[i];
            ldsW8B(act, i >> 5, i & 31, v.x, v.y, v.z, v.w);
        }
        if (tid < 192) rbfs[tid / 6][tid % 6] = rbf0[(size_t)e0 * NRC + tid];
    }
    __syncthreads();

    const int ar = lane & 15;
    const int koff = (lane >> 4) * 8;
    f32x4 aj[2], ak[2];
#pragma unroll
    for (int mt = 0; mt < 2; mt++) {
        f32x4 cj = {0.f, 0.f, 0.f, 0.f};
        f32x4 ck = {0.f, 0.f, 0.f, 0.f};
#pragma unroll
        for (int ks = 0; ks < 4; ks++) {
            bf16x8 a = ldsA(act, mt * 16 + ar, ks * 32 + koff);
            cj = __builtin_amdgcn_mfma_f32_16x16x32_bf16(a, Bji[ks], cj, 0, 0, 0);
            ck = __builtin_amdgcn_mfma_f32_16x16x32_bf16(a, Bkj[ks], ck, 0, 0, 0);
        }
        aj[mt] = cj; ak[mt] = ck;
    }
    // deferred down-projection weights: latency hides under epilogue + barrier
    bf16x8 Bd[4];
#pragma unroll
    for (int ks = 0; ks < 4; ks++)
        Bd[ks] = *(const bf16x8*)(Pdown + (size_t)((ks * 4 + ntd) * 64 + lane) * 8);
    __syncthreads();

    const int ch = w * 16 + (lane & 15);
    const int rg = (lane >> 4) * 4;
    {
        float bjv = bji[ch], bkv = bkj[ch];
        float wr[6];
#pragma unroll
        for (int q = 0; q < 6; q++) wr[q] = Wrbf_c[q * HC + ch];
#pragma unroll
        for (int mt = 0; mt < 2; mt++) {
#pragma unroll
            for (int r = 0; r < 4; r++) {
                int m = mt * 16 + rg + r;
                float rv = 0.f;
#pragma unroll
                for (int q = 0; q < 6; q++) rv += rbfs[m][q] * wr[q];
                xji_out[(size_t)(e0 + m) * HC + ch] = selu_f(aj[mt][r] + bjv);
                float xk = selu_f(ak[mt][r] + bkv) * rv;
                ldsW(act, m, ch, f2bf(xk));
            }
        }
    }
    __syncthreads();

    f32x4 cd = {0.f, 0.f, 0.f, 0.f};
#pragma unroll
    for (int ks = 0; ks < 4; ks++) {
        bf16x8 a = ldsA(act, mtd * 16 + ar, ks * 32 + koff);
        cd = __builtin_amdgcn_mfma_f32_16x16x32_bf16(a, Bd[ks], cd, 0, 0, 0);
    }
    const int chd = ntd * 16 + (lane & 15);
#pragma unroll
    for (int r = 0; r < 4; r++)
        xkjd_out[(size_t)(e0 + mtd * 16 + rg + r) * IC + chd] = selu_f(cd[r]);
}

// ---------------- triplet v8: 16-trip slabs, global_load_lds staging, high occupancy ----------------
#define T2_IMG_B 18816   // 16*1176
#define S2_IMG_B 2688    // 16*168
#define LDS2_TOT (T2_IMG_B + S2_IMG_B + 64 + 64 + 64)
__global__ __launch_bounds__(256) void triplet_mfma8(
    const float* __restrict__ sbf, const float* __restrict__ tmat,
    const unsigned short* __restrict__ Wt_pack,
    const unsigned short* __restrict__ Ws_pack,
    const float* __restrict__ xkjd,
    const int* __restrict__ idx_kj, const int* __restrict__ idx_ji,
    float* __restrict__ seg, int nslab) {
    __shared__ __align__(16) char lds[LDS2_TOT];
    char* t_img = lds;
    char* s_img = lds + T2_IMG_B;
    int* kj_s = (int*)(lds + T2_IMG_B + S2_IMG_B + 64);
    int* ji_s = kj_s + 16;
    const int tid = threadIdx.x;
    const int lane = tid & 63;
    const int w = tid >> 6;
    const int lr = lane & 15;
    const int lq = lane >> 4;
    const int ch = w * 16 + lr;

    bf16x8 bt_w[T_KSTEPS], bs_w[S_KSTEPS];
#pragma unroll
    for (int s = 0; s < T_KSTEPS; s++)
        bt_w[s] = *(const bf16x8*)(Wt_pack + (size_t)((s * 4 + w) * 64 + lane) * 8);
#pragma unroll
    for (int s = 0; s < S_KSTEPS; s++)
        bs_w[s] = *(const bf16x8*)(Ws_pack + (size_t)((s * 4 + w) * 64 + lane) * 8);

    for (int slab = blockIdx.x; slab < nslab; slab += gridDim.x) {
        const size_t t0 = (size_t)slab * 16;
        const char* tsrc = (const char*)tmat + (size_t)slab * T2_IMG_B;
        const char* ssrc = (const char*)sbf + (size_t)slab * S2_IMG_B;

        for (int i = w; i < 22; i += 4) {
            if (i < 19) {
                int off = i * 1024 + lane * 16;
                if (off < T2_IMG_B) gl_lds16(tsrc + off, t_img + off);
            } else {
                int off = (i - 19) * 1024 + lane * 16;
                if (off < S2_IMG_B) gl_lds16(ssrc + off, s_img + off);
            }
        }
        if (tid < 16) { kj_s[tid] = idx_kj[t0 + tid]; ji_s[tid] = idx_ji[t0 + tid]; }
        __syncthreads();

        f32x4 acc_t = {0.f, 0.f, 0.f, 0.f};
        f32x4 acc_s = {0.f, 0.f, 0.f, 0.f};
        {
            const char* tp = t_img + lr * 1176 + lq * 32;
#pragma unroll
            for (int ks = 0; ks < T_KSTEPS; ks++) {
                f32x2 p0 = *(const f32x2*)(tp + ks * 128);
                f32x2 p1 = *(const f32x2*)(tp + ks * 128 + 8);
                f32x2 p2 = *(const f32x2*)(tp + ks * 128 + 16);
                f32x2 p3 = *(const f32x2*)(tp + ks * 128 + 24);
                union { unsigned u[4]; bf16x8 v; } a;
                a.u[0] = cvtpk(p0.x, p0.y); a.u[1] = cvtpk(p1.x, p1.y);
                a.u[2] = cvtpk(p2.x, p2.y); a.u[3] = cvtpk(p3.x, p3.y);
                acc_t = __builtin_amdgcn_mfma_f32_16x16x32_bf16(a.v, bt_w[ks], acc_t, 0, 0, 0);
            }
            const char* sp = s_img + lr * 168 + lq * 32;
#pragma unroll
            for (int ks = 0; ks < S_KSTEPS; ks++) {
                f32x2 p0 = *(const f32x2*)(sp + ks * 128);
                f32x2 p1 = *(const f32x2*)(sp + ks * 128 + 8);
                f32x2 p2 = *(const f32x2*)(sp + ks * 128 + 16);
                f32x2 p3 = *(const f32x2*)(sp + ks * 128 + 24);
                union { unsigned u[4]; bf16x8 v; } a;
                a.u[0] = cvtpk(p0.x, p0.y); a.u[1] = cvtpk(p1.x, p1.y);
                a.u[2] = cvtpk(p2.x, p2.y); a.u[3] = cvtpk(p3.x, p3.y);
                acc_s = __builtin_amdgcn_mfma_f32_16x16x32_bf16(a.v, bs_w[ks], acc_s, 0, 0, 0);
            }
        }

#pragma unroll
        for (int r = 0; r < 4; r++) {
            int ml = lq * 4 + r;
            float y = xkjd[(size_t)kj_s[ml] * IC + ch] * acc_s[r] * acc_t[r];
            atomicAdd(&seg[(size_t)ji_s[ml] * IC + ch], y);
        }
        __syncthreads();
    }
}

// ---------------- edge back: M=32, stage-wise weight double-buffer, 2 blocks/CU ----------------
__global__ __launch_bounds__(512, 4) void edge_back_mfma(
    const float* __restrict__ seg, const float* __restrict__ xji,
    const float* __restrict__ x1, const float* __restrict__ rbf0,
    const unsigned short* __restrict__ Pup,
    const unsigned short* __restrict__ Prb1, const unsigned short* __restrict__ Prb2,
    const unsigned short* __restrict__ Plin,
    const unsigned short* __restrict__ Pra10, const unsigned short* __restrict__ Pra20,
    const unsigned short* __restrict__ Pra11, const unsigned short* __restrict__ Pra21,
    const float* __restrict__ bb1, const float* __restrict__ bb2,
    const float* __restrict__ blin,
    const float* __restrict__ ba1, const float* __restrict__ ba2,
    const float* __restrict__ Wrbf,
    float* __restrict__ e1_out, float* __restrict__ e2_out) {
    __shared__ __align__(16) unsigned short act[32 * 128];
    __shared__ float rbfs[32][8];
    const int tid = threadIdx.x;
    const int lane = tid & 63;
    const int w = tid >> 6;
    const int e0 = blockIdx.x * 32;
    const int ch = w * 16 + (lane & 15);
    const int rg = (lane >> 4) * 4;

    bf16x8 BA[4], BB[4];
#define LOADW(DST, P, N)                                                        \
    _Pragma("unroll")                                                           \
    for (int ks = 0; ks < N; ks++)                                              \
        DST[ks] = *(const bf16x8*)((P) + (size_t)((ks * 8 + w) * 64 + lane) * 8);

    LOADW(BA, Pup, 2)

    {
        const float4* s4 = (const float4*)(seg + (size_t)e0 * IC);
        float4 v = s4[tid];
        ldsW8B(act, tid >> 4, tid & 15, v.x, v.y, v.z, v.w);
        if (tid < 192) rbfs[tid / 6][tid % 6] = rbf0[(size_t)e0 * NRC + tid];
    }
    float skip[2][4], x1v[2][4];
#pragma unroll
    for (int mt = 0; mt < 2; mt++)
#pragma unroll
        for (int r = 0; r < 4; r++) {
            skip[mt][r] = xji[(size_t)(e0 + mt * 16 + rg + r) * HC + ch];
            x1v[mt][r]  = x1 [(size_t)(e0 + mt * 16 + rg + r) * HC + ch];
        }
    __syncthreads();

    f32x4 acc[2];
    float h[2][4];

    mm2<2>(act, BA, lane, acc);
    LOADW(BB, Prb1, 4)
    __syncthreads();
#pragma unroll
    for (int mt = 0; mt < 2; mt++)
#pragma unroll
        for (int r = 0; r < 4; r++) {
            h[mt][r] = selu_f(acc[mt][r]) + skip[mt][r];
            ldsW(act, mt * 16 + rg + r, ch, f2bf(h[mt][r]));
            skip[mt][r] = h[mt][r];
        }
    __syncthreads();

    mm2<4>(act, BB, lane, acc);
    LOADW(BA, Prb2, 4)
    __syncthreads();
    {
        float bv = bb1[ch];
#pragma unroll
        for (int mt = 0; mt < 2; mt++)
#pragma unroll
            for (int r = 0; r < 4; r++)
                ldsW(act, mt * 16 + rg + r, ch, f2bf(selu_f(acc[mt][r] + bv)));
    }
    __syncthreads();

    mm2<4>(act, BA, lane, acc);
    LOADW(BB, Plin, 4)
    __syncthreads();
    {
        float bv = bb2[ch];
#pragma unroll
        for (int mt = 0; mt < 2; mt++)
#pragma unroll
            for (int r = 0; r < 4; r++) {
                h[mt][r] = skip[mt][r] + selu_f(acc[mt][r] + bv);
                ldsW(act, mt * 16 + rg + r, ch, f2bf(h[mt][r]));
            }
    }
    __syncthreads();

    mm2<4>(act, BB, lane, acc);
    LOADW(BA, Pra10, 4)
    __syncthreads();
    {
        float bv = blin[ch];
#pragma unroll
        for (int mt = 0; mt < 2; mt++)
#pragma unroll
            for (int r = 0; r < 4; r++) {
                h[mt][r] = selu_f(acc[mt][r] + bv) + x1v[mt][r];
                ldsW(act, mt * 16 + rg + r, ch, f2bf(h[mt][r]));
                skip[mt][r] = h[mt][r];
            }
    }
    __syncthreads();

    mm2<4>(act, BA, lane, acc);
    LOADW(BB, Pra20, 4)
    __syncthreads();
    {
        float bv = ba1[ch];
#pragma unroll
        for (int mt = 0; mt < 2; mt++)
#pragma unroll
            for (int r = 0; r < 4; r++)
                ldsW(act, mt * 16 + rg + r, ch, f2bf(selu_f(acc[mt][r] + bv)));
    }
    __syncthreads();

    mm2<4>(act, BB, lane, acc);
    LOADW(BA, Pra11, 4)
    __syncthreads();
    {
        float bv = ba2[ch];
#pragma unroll
        for (int mt = 0; mt < 2; mt++)
#pragma unroll
            for (int r = 0; r < 4; r++) {
                h[mt][r] = skip[mt][r] + selu_f(acc[mt][r] + bv);
                ldsW(act, mt * 16 + rg + r, ch, f2bf(h[mt][r]));
                skip[mt][r] = h[mt][r];
            }
    }
    __syncthreads();

    mm2<4>(act, BA, lane, acc);
    LOADW(BB, Pra21, 4)
    __syncthreads();
    {
        float bv = ba1[HC + ch];
#pragma unroll
        for (int mt = 0; mt < 2; mt++)
#pragma unroll
            for (int r = 0; r < 4; r++)
                ldsW(act, mt * 16 + rg + r, ch, f2bf(selu_f(acc[mt][r] + bv)));
    }
    __syncthreads();

    mm2<4>(act, BB, lane, acc);
    {
        float bv = ba2[HC + ch];
        float wr[6];
#pragma unroll
        for (int q = 0; q < 6; q++) wr[q] = Wrbf[q * HC + ch];
#pragma unroll
        for (int mt = 0; mt < 2; mt++)
#pragma unroll
            for (int r = 0; r < 4; r++) {
                int m = mt * 16 + rg + r;
                float v = skip[mt][r] + selu_f(acc[mt][r] + bv);
                float rv = 0.f;
#pragma unroll
                for (int q = 0; q < 6; q++) rv += rbfs[m][q] * wr[q];
                size_t e = (size_t)(e0 + m);
                e1_out[e * HC + ch] = v;
                e2_out[e * HC + ch] = rv * v;
            }
    }
#undef LOADW
}

extern "C" void kernel_launch(void* const* d_in, const int* in_sizes, int n_in,
                              void* d_out, int out_size, void* d_ws, size_t ws_size,
                              hipStream_t stream) {
    const float* x1     = (const float*)d_in[0];
    const float* rbf0   = (const float*)d_in[1];
    const float* sbf    = (const float*)d_in[2];
    const float* tmat   = (const float*)d_in[3];
    const float* W_rbf1 = (const float*)d_in[5];
    const float* W_rbf2 = (const float*)d_in[6];
    const float* W_sbf1 = (const float*)d_in[7];
    const float* W_sbf2 = (const float*)d_in[8];
    const float* W_t1   = (const float*)d_in[9];
    const float* W_t2   = (const float*)d_in[10];
    const float* W_rbf  = (const float*)d_in[11];
    const float* W_kj   = (const float*)d_in[12];
    const float* b_kj   = (const float*)d_in[13];
    const float* W_ji   = (const float*)d_in[14];
    const float* b_ji   = (const float*)d_in[15];
    const float* W_down = (const float*)d_in[16];
    const float* W_up   = (const float*)d_in[17];
    const float* W_lin  = (const float*)d_in[18];
    const float* b_lin  = (const float*)d_in[19];
    const float* resbW1 = (const float*)d_in[20];
    const float* resbb1 = (const float*)d_in[21];
    const float* resbW2 = (const float*)d_in[22];
    const float* resbb2 = (const float*)d_in[23];
    const float* resaW1 = (const float*)d_in[24];
    const float* resab1 = (const float*)d_in[25];
    const float* resaW2 = (const float*)d_in[26];
    const float* resab2 = (const float*)d_in[27];
    const int* idx_kj   = (const int*)d_in[28];
    const int* idx_ji   = (const int*)d_in[29];

    float* ws = (float*)d_ws;
    float* Wrbf_c = ws;                                    // 768 f32
    unsigned short* u0 = (unsigned short*)(ws + 768);
    unsigned short* Wt_pack = u0;              // 20480
    unsigned short* Ws_pack = Wt_pack + 20480; // 4096
    unsigned short* Pji   = Ws_pack + 4096;    // 16384
    unsigned short* Pkj   = Pji + 16384;
    unsigned short* Pdown = Pkj + 16384;       // 8192
    unsigned short* Pup   = Pdown + 8192;      // 8192
    unsigned short* Prb1  = Pup + 8192;        // 16384
    unsigned short* Prb2  = Prb1 + 16384;
    unsigned short* Plin  = Prb2 + 16384;
    unsigned short* Pra10 = Plin + 16384;
    unsigned short* Pra20 = Pra10 + 16384;
    unsigned short* Pra11 = Pra20 + 16384;
    unsigned short* Pra21 = Pra11 + 16384;
    float* xkjd = ws + 768 + 94208;
    float* seg  = xkjd + (size_t)EDGES * IC;

    float* e1_out = (float*)d_out;
    float* e2_out = e1_out + (size_t)EDGES * HC;
    float* xji    = e1_out;  // park x_ji in the e1 output region

    combos_kernel<<<64, 256, 0, stream>>>(W_rbf1, W_rbf2, W_sbf1, W_sbf2, W_t1, W_t2,
                                          W_ji, W_kj, W_down, W_up, resbW1, resbW2,
                                          W_lin, resaW1, resaW2,
                                          Wrbf_c, Wt_pack, Ws_pack,
                                          Pji, Pkj, Pdown, Pup, Prb1, Prb2, Plin,
                                          Pra10, Pra20, Pra11, Pra21);
    edge_front_mfma<<<EDGES / 32, 512, 0, stream>>>(x1, rbf0, Pji, Pkj, Pdown,
                                                    b_ji, b_kj, Wrbf_c, xji, xkjd, seg);
    triplet_mfma8<<<4096, 256, 0, stream>>>(sbf, tmat, Wt_pack, Ws_pack, xkjd,
                                            idx_kj, idx_ji, seg, TRIPS / 16);
    edge_back_mfma<<<EDGES / 32, 512, 0, stream>>>(seg, xji, x1, rbf0,
                                                   Pup, Prb1, Prb2, Plin,
                                                   Pra10, Pra20, Pra11, Pra21,
                                                   resbb1, resbb2, b_lin,
                                                   resab1, resab2, W_rbf,
                                                   e1_out, e2_out);
}